// Round 7
// baseline (498.287 us; speedup 1.0000x reference)
//
#include <hip/hip_runtime.h>
#include <math.h>

// ---- problem constants ----
#define NB 2
#define NS 2048
#define NE 768
#define NF 3072
#define NHEAD 12
#define NTOK 4096   // B*S

typedef __bf16 bf16;
typedef __bf16 bf16x4 __attribute__((ext_vector_type(4)));
typedef __bf16 bf16x8 __attribute__((ext_vector_type(8)));
typedef float  f32x4  __attribute__((ext_vector_type(4)));

__device__ __forceinline__ f32x4 mfma_bf16(bf16x8 a, bf16x8 b, f32x4 c) {
  return __builtin_amdgcn_mfma_f32_16x16x32_bf16(a, b, c, 0, 0, 0);
}

__device__ __forceinline__ float fast_exp2(float x) {
#if __has_builtin(__builtin_amdgcn_exp2f)
  return __builtin_amdgcn_exp2f(x);
#else
  return exp2f(x);
#endif
}

// async global->LDS, 16B per lane. LDS dest must be wave-uniform base + lane*16.
__device__ __forceinline__ void glds16(const void* g, void* l) {
  __builtin_amdgcn_global_load_lds((const __attribute__((address_space(1))) void*)g,
                                   (__attribute__((address_space(3))) void*)l,
                                   16, 0, 0);
}

// XCD-band swizzle: block i -> XCD i&7 (round-robin dispatch assumption); give
// each XCD a contiguous band of gridDim.y/8 M-panels for L2 A-reuse.
// Requires gridDim.y % 8 == 0 (true for all launches here: GY=32).
__device__ __forceinline__ void swz_xy(int& bx, int& by) {
  int gx = gridDim.x;
  int i = by*gx + bx;
  int xcd = i & 7, s = i >> 3;
  int bands = gridDim.y >> 3;
  by = xcd*bands + s / gx;
  bx = s % gx;
}

// ---------------- weight prep: fp32 -> bf16 (+ reshapes/concat) ----------------
__global__ void prep_kernel(const float* __restrict__ in_proj, const float* __restrict__ out_proj,
                            const float* __restrict__ ffn1_w, const float* __restrict__ ffn1_b,
                            const float* __restrict__ ffn2_w,
                            const float* __restrict__ hA_w1, const float* __restrict__ hA_b1,
                            const float* __restrict__ hA_w2, const float* __restrict__ hA_b2,
                            const float* __restrict__ hB_w1, const float* __restrict__ hB_b1,
                            const float* __restrict__ hB_w2,
                            const float* __restrict__ task,
                            bf16* __restrict__ Wqkv, bf16* __restrict__ Wo, bf16* __restrict__ W2,
                            bf16* __restrict__ W1ab, float* __restrict__ b1ab,
                            bf16* __restrict__ WBp, bf16* __restrict__ Wc,
                            bf16* __restrict__ task_bf)
{
  __shared__ float tb[64*130];
  int stride = gridDim.x * blockDim.x;
  int t0 = blockIdx.x * blockDim.x + threadIdx.x;
  // q rows (first 768) pre-scaled by (1/sqrt(HD)) * log2(e) so flash can use exp2
  const float QS = 0.125f * 1.44269504088896f;
  for (int i = t0; i < 2304*768; i += stride)
    Wqkv[i] = (bf16)(i < 768*768 ? in_proj[i] * QS : in_proj[i]);
  for (int i = t0; i < 768*768;  i += stride) Wo[i]   = (bf16)out_proj[i];
  for (int i = t0; i < 768*3072; i += stride) W2[i]   = (bf16)ffn2_w[i];
  for (int i = t0; i < 256*128;  i += stride)
    W1ab[i] = (bf16)(i < 128*128 ? hA_w1[i] : hB_w1[i - 128*128]);
  for (int i = t0; i < 256; i += stride) b1ab[i] = (i < 128) ? hA_b1[i] : hB_b1[i-128];
  for (int i = t0; i < NTOK*128; i += stride) task_bf[i] = (bf16)task[i];

  // WBp[n=(r*128+h)][e] = hB_w2[r*768+e][h] via 64x128 LDS transpose (coalesced both sides)
  for (int j0 = blockIdx.x*64; j0 < 3072; j0 += gridDim.x*64) {
    __syncthreads();
    for (int i = threadIdx.x; i < 64*128; i += 256) {
      int jr = i >> 7, hh = i & 127;
      tb[jr*130 + hh] = hB_w2[(long)(j0 + jr)*128 + hh];
    }
    __syncthreads();
    int r = j0 / 768, e0 = j0 % 768;
    for (int i = threadIdx.x; i < 128*64; i += 256) {
      int hh = i >> 6, jr = i & 63;
      WBp[(long)(r*128 + hh)*768 + e0 + jr] = (bf16)tb[jr*130 + hh];
    }
  }

  // Wc[f][0:768]=ffn1_w ; [768+h*4+r]=hA_w2[(f*4+r)][h] ; [1280+r]=hA_b2[f*4+r] ;
  // [1284]=ffn1_b[f] ; [1285:1312]=0.   hA_w2 read contiguously (i = r*128+h).
  for (int f = blockIdx.x; f < 3072; f += gridDim.x) {
    const float* hrow = hA_w2 + (long)f*512;
    bf16* wrow = Wc + (long)f*1312;
    for (int c = threadIdx.x; c < 768; c += 256) wrow[c] = (bf16)ffn1_w[(long)f*768 + c];
    for (int i = threadIdx.x; i < 512; i += 256) {
      int r = i >> 7, h = i & 127;
      wrow[768 + h*4 + r] = (bf16)hrow[i];
    }
    if (threadIdx.x < 4)        wrow[1280 + threadIdx.x] = (bf16)hA_b2[f*4 + threadIdx.x];
    else if (threadIdx.x == 4)  wrow[1284] = (bf16)ffn1_b[f];
    else if (threadIdx.x < 32)  wrow[1280 + threadIdx.x] = (bf16)0.f;
  }
}

// ---------------- RMSNorm (fp32 in -> bf16 out, arbitrary out row stride) ------
__global__ __launch_bounds__(256) void rmsnorm_k(const float* __restrict__ x,
                                                 const float* __restrict__ w,
                                                 bf16* __restrict__ out, int ld_out)
{
  __shared__ float red[4];
  long t = blockIdx.x;
  const float* xr = x + t*NE;
  float ss = 0.f;
  #pragma unroll
  for (int i = 0; i < 3; i++) { float v = xr[threadIdx.x + i*256]; ss += v*v; }
  #pragma unroll
  for (int d = 1; d < 64; d <<= 1) ss += __shfl_xor(ss, d, 64);
  if ((threadIdx.x & 63) == 0) red[threadIdx.x >> 6] = ss;
  __syncthreads();
  float tot = red[0] + red[1] + red[2] + red[3];
  float scale = rsqrtf(tot * (1.f/768.f) + 1.1920928955078125e-07f);
  #pragma unroll
  for (int i = 0; i < 3; i++) {
    int idx = threadIdx.x + i*256;
    out[t*ld_out + idx] = (bf16)(xr[idx] * scale * w[idx]);
  }
}

// ---------------- generic bf16 GEMM (LDS path), C = A * B^T -------------------
// Used only for K10 (3 blocks/CU, compute-heaviest: LDS halves global traffic).
template<typename OutT, bool RELU, bool BIAS, bool RES>
__global__ __launch_bounds__(256) void gemm_bt(const bf16* __restrict__ A,
                                               const bf16* __restrict__ Bm,
                                               OutT* __restrict__ C,
                                               const float* __restrict__ bias,
                                               const float* __restrict__ res,
                                               int K, int lda, int ldb, int ldc)
{
  __shared__ bf16 As[2][128*32];
  __shared__ bf16 Bs[2][128*32];
  const int tid = threadIdx.x;
  int bx = blockIdx.x, by = blockIdx.y;
  swz_xy(bx, by);
  const int m0 = by * 128;
  const int n0 = bx * 128;
  const int w = tid >> 6, lane = tid & 63;
  const int quad = lane >> 4, l16 = lane & 15;
  const int wy = w >> 1, wx = w & 1;

  f32x4 acc[4][4];
  #pragma unroll
  for (int i = 0; i < 4; i++)
    #pragma unroll
    for (int j = 0; j < 4; j++) acc[i][j] = (f32x4){0.f,0.f,0.f,0.f};

  const int c0 = tid, c1 = tid + 256;
  const bf16* pA0 = A  + (long)(m0 + (c0 >> 2))*lda + (c0 & 3)*8;
  const bf16* pA1 = A  + (long)(m0 + (c1 >> 2))*lda + (c1 & 3)*8;
  const bf16* pB0 = Bm + (long)(n0 + (c0 >> 2))*ldb + (c0 & 3)*8;
  const bf16* pB1 = Bm + (long)(n0 + (c1 >> 2))*ldb + (c1 & 3)*8;
  auto stage = [&](int buf) {
    glds16(pA0, (void*)(&As[buf][c0*8]));
    glds16(pA1, (void*)(&As[buf][c1*8]));
    glds16(pB0, (void*)(&Bs[buf][c0*8]));
    glds16(pB1, (void*)(&Bs[buf][c1*8]));
    pA0 += 32; pA1 += 32; pB0 += 32; pB1 += 32;
  };

  stage(0);
  __builtin_amdgcn_s_waitcnt(0);
  __syncthreads();

  const int nsteps = K >> 5;
  for (int s = 0; s < nsteps; ++s) {
    const int cur = s & 1;
    if (s + 1 < nsteps) stage(cur ^ 1);

    bf16x8 af[4], bfr[4];
    #pragma unroll
    for (int mi = 0; mi < 4; ++mi)
      af[mi] = *(const bf16x8*)(&As[cur][(wy*64 + mi*16 + l16)*32 + quad*8]);
    #pragma unroll
    for (int ni = 0; ni < 4; ++ni)
      bfr[ni] = *(const bf16x8*)(&Bs[cur][(wx*64 + ni*16 + l16)*32 + quad*8]);
    #pragma unroll
    for (int mi = 0; mi < 4; ++mi)
      #pragma unroll
      for (int ni = 0; ni < 4; ++ni)
        acc[mi][ni] = mfma_bf16(af[mi], bfr[ni], acc[mi][ni]);

    __builtin_amdgcn_s_waitcnt(0);
    __syncthreads();
  }

  #pragma unroll
  for (int mi = 0; mi < 4; ++mi)
    #pragma unroll
    for (int ni = 0; ni < 4; ++ni) {
      int col = n0 + wx*64 + ni*16 + l16;
      #pragma unroll
      for (int r = 0; r < 4; ++r) {
        long row = m0 + wy*64 + mi*16 + quad*4 + r;
        float v = acc[mi][ni][r];
        if (BIAS) v += bias[col];
        if (RES)  v += res[row*ldc + col];
        if (RELU) v = v > 0.f ? v : 0.f;
        C[row*ldc + col] = (OutT)v;
      }
    }
}

// ---------------- register-pipeline GEMM, no LDS / no barriers ----------------
// 128Mx64N tile, wave = 64Mx32N. Each wave loads its MFMA fragments directly
// global->VGPR with a 2-deep software pipeline; the compiler's dependency-driven
// s_waitcnt leaves the prefetched set in flight (the fine-grained vmcnt the
// barrier path can't express — R5/R6 evidence). A/B fetched 2x per block
// (wave-pair redundancy) — absorbed by L1/L2. K must be a multiple of 64.
template<typename OutT, bool RELU, bool BIAS, bool RES>
__global__ __launch_bounds__(256) void gemm_reg64(const bf16* __restrict__ A,
                                                  const bf16* __restrict__ Bm,
                                                  OutT* __restrict__ C,
                                                  const float* __restrict__ bias,
                                                  const float* __restrict__ res,
                                                  int K, int lda, int ldb, int ldc)
{
  const int tid = threadIdx.x;
  int bx = blockIdx.x, by = blockIdx.y;
  swz_xy(bx, by);
  const int m0 = by * 128, n0 = bx * 64;
  const int w = tid >> 6, lane = tid & 63;
  const int quad = lane >> 4, l16 = lane & 15;
  const int wy = w >> 1, wx = w & 1;

  f32x4 acc[4][2];
  #pragma unroll
  for (int i = 0; i < 4; i++)
    #pragma unroll
    for (int j = 0; j < 2; j++) acc[i][j] = (f32x4){0.f,0.f,0.f,0.f};

  const bf16* pa[4];
  const bf16* pb[2];
  #pragma unroll
  for (int mi = 0; mi < 4; ++mi)
    pa[mi] = A + (long)(m0 + wy*64 + mi*16 + l16)*lda + quad*8;
  #pragma unroll
  for (int ni = 0; ni < 2; ++ni)
    pb[ni] = Bm + (long)(n0 + wx*32 + ni*16 + l16)*ldb + quad*8;

  auto ldf = [&](int s, bf16x8 (&fa)[4], bf16x8 (&fb)[2]) {
    #pragma unroll
    for (int mi = 0; mi < 4; ++mi) fa[mi] = *(const bf16x8*)(pa[mi] + (long)s*32);
    #pragma unroll
    for (int ni = 0; ni < 2; ++ni) fb[ni] = *(const bf16x8*)(pb[ni] + (long)s*32);
  };

  const int n = K >> 5;                 // even at all call sites (4, 24, 96)
  bf16x8 a0[4], b0[2], a1[4], b1[2];
  ldf(0, a0, b0);
  ldf(1, a1, b1);
  for (int s = 0; s < n; s += 2) {
    #pragma unroll
    for (int mi = 0; mi < 4; ++mi)
      #pragma unroll
      for (int ni = 0; ni < 2; ++ni)
        acc[mi][ni] = mfma_bf16(a0[mi], b0[ni], acc[mi][ni]);
    if (s + 2 < n) ldf(s + 2, a0, b0);
    #pragma unroll
    for (int mi = 0; mi < 4; ++mi)
      #pragma unroll
      for (int ni = 0; ni < 2; ++ni)
        acc[mi][ni] = mfma_bf16(a1[mi], b1[ni], acc[mi][ni]);
    if (s + 3 < n) ldf(s + 3, a1, b1);
  }

  #pragma unroll
  for (int mi = 0; mi < 4; ++mi)
    #pragma unroll
    for (int ni = 0; ni < 2; ++ni) {
      int col = n0 + wx*32 + ni*16 + l16;
      #pragma unroll
      for (int r = 0; r < 4; ++r) {
        long row = m0 + wy*64 + mi*16 + quad*4 + r;
        float v = acc[mi][ni][r];
        if (BIAS) v += bias[col];
        if (RES)  v += res[row*ldc + col];
        if (RELU) v = v > 0.f ? v : 0.f;
        C[row*ldc + col] = (OutT)v;
      }
    }
}

// ---- QKV GEMM, register-pipeline 128x128 variant; split epilogue:
// cols<1536 -> Qkv[t][2304]; V block -> Vt[bh][d][s] directly.
__global__ __launch_bounds__(256) void gemm_qkv(const bf16* __restrict__ A,
                                                const bf16* __restrict__ Bm,
                                                bf16* __restrict__ Qkv,
                                                bf16* __restrict__ Vt)
{
  const int tid = threadIdx.x;
  int bx = blockIdx.x, by = blockIdx.y;
  swz_xy(bx, by);
  const int m0 = by * 128, n0 = bx * 128;
  const int w = tid >> 6, lane = tid & 63;
  const int quad = lane >> 4, l16 = lane & 15;
  const int wy = w >> 1, wx = w & 1;

  f32x4 acc[4][4];
  #pragma unroll
  for (int i = 0; i < 4; i++)
    #pragma unroll
    for (int j = 0; j < 4; j++) acc[i][j] = (f32x4){0.f,0.f,0.f,0.f};

  const bf16* pa[4];
  const bf16* pb[4];
  #pragma unroll
  for (int mi = 0; mi < 4; ++mi)
    pa[mi] = A + (long)(m0 + wy*64 + mi*16 + l16)*768 + quad*8;
  #pragma unroll
  for (int ni = 0; ni < 4; ++ni)
    pb[ni] = Bm + (long)(n0 + wx*64 + ni*16 + l16)*768 + quad*8;

  auto ldf = [&](int s, bf16x8 (&fa)[4], bf16x8 (&fb)[4]) {
    #pragma unroll
    for (int mi = 0; mi < 4; ++mi) fa[mi] = *(const bf16x8*)(pa[mi] + (long)s*32);
    #pragma unroll
    for (int ni = 0; ni < 4; ++ni) fb[ni] = *(const bf16x8*)(pb[ni] + (long)s*32);
  };

  bf16x8 a0[4], b0[4], a1[4], b1[4];
  ldf(0, a0, b0);
  ldf(1, a1, b1);
  for (int s = 0; s < 24; s += 2) {      // K=768
    #pragma unroll
    for (int mi = 0; mi < 4; ++mi)
      #pragma unroll
      for (int ni = 0; ni < 4; ++ni)
        acc[mi][ni] = mfma_bf16(a0[mi], b0[ni], acc[mi][ni]);
    if (s + 2 < 24) ldf(s + 2, a0, b0);
    #pragma unroll
    for (int mi = 0; mi < 4; ++mi)
      #pragma unroll
      for (int ni = 0; ni < 4; ++ni)
        acc[mi][ni] = mfma_bf16(a1[mi], b1[ni], acc[mi][ni]);
    if (s + 3 < 24) ldf(s + 3, a1, b1);
  }

  const int bb = m0 >> 11;                  // batch (tile is 2048-aligned)
  #pragma unroll
  for (int mi = 0; mi < 4; ++mi)
    #pragma unroll
    for (int ni = 0; ni < 4; ++ni) {
      int col = n0 + wx*64 + ni*16 + l16;
      #pragma unroll
      for (int r = 0; r < 4; ++r) {
        long row = m0 + wy*64 + mi*16 + quad*4 + r;
        bf16 v = (bf16)acc[mi][ni][r];
        if (col < 1536) {
          Qkv[row*2304 + col] = v;
        } else {
          int vc = col - 1536;
          int hh = vc >> 6, d = vc & 63;
          long srow = row & (NS-1);
          Vt[((long)(bb*NHEAD + hh)*64 + d)*NS + srow] = v;
        }
      }
    }
}

// ---------------- flash attention v3: register-resident P ----------------------
// S^T = mfma(K, Q); S^T's C-layout (q=l16, kv=quad*4+r) IS the PV A-operand
// layout under k-mapping j<4 -> quad*4+j, j>=4 -> 16+quad*4+(j-4).
// No online-softmax (|s|<~5, exp2 safe, shift-invariant). q pre-scaled by
// 0.125*log2e. XOR-swizzled K/V LDS, dbuf staging.
__global__ __launch_bounds__(256) void flash_attn(const bf16* __restrict__ Qkv,
                                                  const bf16* __restrict__ Vt,
                                                  bf16* __restrict__ Ctx)
{
  __shared__ bf16 Ks[2][64*64];
  __shared__ bf16 Vs[2][64*64];
  __shared__ float Ls[4][16];

  const int tid = threadIdx.x;
  const int w = tid >> 6, lane = tid & 63;
  const int quad = lane >> 4, l16 = lane & 15;
  const int bh = blockIdx.y;
  const int b = bh / NHEAD, h = bh % NHEAD;
  const int q0 = blockIdx.x * 64;
  const long tq = (long)(b*NS + q0 + w*16 + l16);

  bf16x8 qf[2];   // q pre-scaled by 0.125*log2e via Wqkv
  qf[0] = *(const bf16x8*)(Qkv + tq*2304 + h*64 + quad*8);
  qf[1] = *(const bf16x8*)(Qkv + tq*2304 + h*64 + 32 + quad*8);

  f32x4 o[4];
  float lsum = 0.f;
  #pragma unroll
  for (int i = 0; i < 4; i++) o[i] = (f32x4){0.f,0.f,0.f,0.f};

  const int c0 = tid, c1 = tid + 256;
  const int r0 = c0 >> 3, g0 = ((c0 & 7) ^ (r0 & 7)) * 8;
  const int r1 = c1 >> 3, g1 = ((c1 & 7) ^ (r1 & 7)) * 8;
  const bf16* kp0 = Qkv + (long)(b*NS + r0)*2304 + 768 + h*64 + g0;
  const bf16* kp1 = Qkv + (long)(b*NS + r1)*2304 + 768 + h*64 + g1;
  const bf16* vp0 = Vt + ((long)bh*64 + r0)*NS + g0;
  const bf16* vp1 = Vt + ((long)bh*64 + r1)*NS + g1;

  auto stage = [&](int buf) {
    glds16(kp0, (void*)(&Ks[buf][c0*8]));
    glds16(kp1, (void*)(&Ks[buf][c1*8]));
    glds16(vp0, (void*)(&Vs[buf][c0*8]));
    glds16(vp1, (void*)(&Vs[buf][c1*8]));
    kp0 += 64*2304; kp1 += 64*2304; vp0 += 64; vp1 += 64;
  };

  stage(0);
  __builtin_amdgcn_s_waitcnt(0);
  __syncthreads();

  for (int t = 0; t < NS/64; ++t) {
    const int cur = t & 1;
    if (t + 1 < NS/64) stage(cur ^ 1);

    // S^T = K Q^T : s[nt] holds kv = nt*16 + quad*4 + r, q = l16
    f32x4 s[4];
    #pragma unroll
    for (int nt = 0; nt < 4; ++nt) {
      s[nt] = (f32x4){0.f,0.f,0.f,0.f};
      #pragma unroll
      for (int kb = 0; kb < 2; ++kb) {
        bf16x8 kf = *(const bf16x8*)(&Ks[cur][(nt*16 + l16)*64 + (((kb*4 + quad) ^ (l16 & 7)))*8]);
        s[nt] = mfma_bf16(kf, qf[kb], s[nt]);   // A=K, B=Q -> S^T
      }
    }
    // P = exp2(S^T) in registers; pack straight into PV A-fragments
    bf16x8 pf[2];
    #pragma unroll
    for (int nt = 0; nt < 4; ++nt)
      #pragma unroll
      for (int r = 0; r < 4; ++r) {
        float p = fast_exp2(s[nt][r]);
        lsum += p;
        pf[nt >> 1][(nt & 1)*4 + r] = (bf16)p;
      }
    // PV: o[dt] += P * V   (B-frag: two b64 reads from Vs, 16 kv apart)
    #pragma unroll
    for (int ntp = 0; ntp < 2; ++ntp)
      #pragma unroll
      for (int dt = 0; dt < 4; ++dt) {
        int row = dt*16 + l16;                       // d
        int cA = ntp*4 + (quad >> 1);
        int base = row*64 + (quad & 1)*4;
        bf16x4 va = *(const bf16x4*)(&Vs[cur][base + ((cA       ^ (row & 7)) << 3)]);
        bf16x4 vb = *(const bf16x4*)(&Vs[cur][base + (((cA + 2) ^ (row & 7)) << 3)]);
        bf16x8 vf = {va[0],va[1],va[2],va[3], vb[0],vb[1],vb[2],vb[3]};
        o[dt] = mfma_bf16(pf[ntp], vf, o[dt]);
      }

    __builtin_amdgcn_s_waitcnt(0);
    __syncthreads();
  }

  // row sums: lane holds q=l16; reduce over quads, then redistribute via LDS
  lsum += __shfl_xor(lsum, 16, 64);
  lsum += __shfl_xor(lsum, 32, 64);
  if (quad == 0) Ls[w][l16] = lsum;       // wave-private
  #pragma unroll
  for (int r = 0; r < 4; ++r) {
    float inv = 1.f / Ls[w][quad*4 + r];
    long trow = (long)(b*NS + q0 + w*16 + quad*4 + r);
    #pragma unroll
    for (int dt = 0; dt < 4; ++dt)
      Ctx[trow*NE + h*64 + dt*16 + l16] = (bf16)(o[dt][r] * inv);
  }
}

// ---------------- per-token: inter + build g/ones/zeros cols of Aext -----------
// 4 waves/block, one token per wave.
__global__ __launch_bounds__(256) void build_g(const bf16* __restrict__ HAB,
                                               const float* __restrict__ P,
                                               const float* __restrict__ hB_b2,
                                               bf16* __restrict__ Aext)
{
  long t = blockIdx.x*4 + (threadIdx.x >> 6);
  int lane = threadIdx.x & 63;
  const bf16* xr = Aext + t*1312;            // cols 0..767 = xn2
  float acc[4] = {0.f, 0.f, 0.f, 0.f};
  for (int i = lane; i < 768; i += 64) {
    float xv = (float)xr[i];
    #pragma unroll
    for (int r = 0; r < 4; ++r) acc[r] += xv * hB_b2[r*768 + i];
  }
  const bf16* hB = HAB + t*256 + 128;
  const float* Pr = P + t*512;
  #pragma unroll
  for (int k = 0; k < 2; ++k) {
    int h = lane + k*64;
    float hv = (float)hB[h];
    #pragma unroll
    for (int r = 0; r < 4; ++r) acc[r] += hv * Pr[r*128 + h];
  }
  #pragma unroll
  for (int r = 0; r < 4; ++r)
    #pragma unroll
    for (int d = 1; d < 64; d <<= 1) acc[r] += __shfl_xor(acc[r], d, 64);

  bf16* grow = Aext + t*1312 + 768;
  const bf16* hA = HAB + t*256;
  #pragma unroll
  for (int j = 0; j < 8; ++j) {
    int idx = lane*8 + j;                    // 0..511
    int h = idx >> 2, r = idx & 3;
    grow[idx] = (bf16)((float)hA[h] * acc[r]);
  }
  if (lane < 4)       Aext[t*1312 + 1280 + lane] = (bf16)acc[lane];
  else if (lane == 4) Aext[t*1312 + 1284] = (bf16)1.0f;
  else if (lane < 32) Aext[t*1312 + 1280 + lane] = (bf16)0.f;
}

// ---------------- host launcher ----------------
extern "C" void kernel_launch(void* const* d_in, const int* in_sizes, int n_in,
                              void* d_out, int out_size, void* d_ws, size_t ws_size,
                              hipStream_t stream)
{
  const float* src      = (const float*)d_in[0];
  const float* task     = (const float*)d_in[1];
  const float* norm1_w  = (const float*)d_in[2];
  const float* norm2_w  = (const float*)d_in[3];
  const float* in_proj  = (const float*)d_in[4];
  const float* out_proj = (const float*)d_in[5];
  const float* ffn1_w   = (const float*)d_in[6];
  const float* ffn1_b   = (const float*)d_in[7];
  const float* ffn2_w   = (const float*)d_in[8];
  const float* ffn2_b   = (const float*)d_in[9];
  const float* hA_w1    = (const float*)d_in[10];
  const float* hA_b1    = (const float*)d_in[11];
  const float* hA_w2    = (const float*)d_in[12];
  const float* hA_b2    = (const float*)d_in[13];
  const float* hB_w1    = (const float*)d_in[14];
  const float* hB_b1    = (const float*)d_in[15];
  const float* hB_w2    = (const float*)d_in[16];
  const float* hB_b2    = (const float*)d_in[17];
  float* out = (float*)d_out;

  char* ws = (char*)d_ws;
  size_t off = 0;
  auto alloc = [&](size_t bytes) { size_t o = off; off += (bytes + 255) & ~(size_t)255; return o; };
  bf16*  Wqkv   = (bf16*)(ws + alloc(2304*768*2));
  bf16*  Wo     = (bf16*)(ws + alloc(768*768*2));
  bf16*  W2     = (bf16*)(ws + alloc(768*3072*2));
  bf16*  W1ab   = (bf16*)(ws + alloc(256*128*2));
  float* b1ab   = (float*)(ws + alloc(256*4));
  bf16*  WBp    = (bf16*)(ws + alloc(512*768*2));
  bf16*  Wc     = (bf16*)(ws + alloc(3072*1312*2));
  bf16*  taskbf = (bf16*)(ws + alloc((size_t)NTOK*128*2));
  bf16*  XC     = (bf16*)(ws + alloc((size_t)NTOK*768*2));    // Xn1, then Ctx
  char*  QKVH   = ws + alloc(25165824);                        // Qkv(18874368)+Vt(6291456) / Hbuf
  bf16*  Qkv    = (bf16*)QKVH;
  bf16*  Vt     = (bf16*)(QKVH + 18874368);
  bf16*  Hbuf   = (bf16*)QKVH;
  float* Src2   = (float*)(ws + alloc((size_t)NTOK*768*4));
  bf16*  Aext   = (bf16*)(ws + alloc((size_t)NTOK*1312*2));
  bf16*  HAB    = (bf16*)(ws + alloc((size_t)NTOK*256*2));
  float* P      = (float*)(ws + alloc((size_t)NTOK*512*4));

  // K0: weight prep / casts
  prep_kernel<<<dim3(1280), 256, 0, stream>>>(in_proj, out_proj, ffn1_w, ffn1_b, ffn2_w,
      hA_w1, hA_b1, hA_w2, hA_b2, hB_w1, hB_b1, hB_w2, task,
      Wqkv, Wo, W2, W1ab, b1ab, WBp, Wc, taskbf);
  // K1: x1 = rmsnorm(src, norm1_w) -> bf16
  rmsnorm_k<<<dim3(NTOK), 256, 0, stream>>>(src, norm1_w, XC, 768);
  // K2: qkv = x1 @ in_proj^T ; V block written directly to Vt
  gemm_qkv<<<dim3(18,32), 256, 0, stream>>>(XC, Wqkv, Qkv, Vt);
  // K4: flash attention -> Ctx (reuses XC)
  flash_attn<<<dim3(32,24), 256, 0, stream>>>(Qkv, Vt, XC);
  // K5: src2 = src + ctx @ out_proj^T
  gemm_reg64<float,false,false,true><<<dim3(12,32), 256, 0, stream>>>(XC, Wo, Src2, nullptr, src, 768, 768, 768, 768);
  // K6: xn2 = rmsnorm(src2, norm2_w) -> Aext cols 0..767 (stride 1312)
  rmsnorm_k<<<dim3(NTOK), 256, 0, stream>>>(Src2, norm2_w, Aext, 1312);
  // K7: HAB = relu(task @ W1ab^T + b1ab)
  gemm_reg64<bf16,true,true,false><<<dim3(4,32), 256, 0, stream>>>(taskbf, W1ab, HAB, b1ab, nullptr, 128, 128, 128, 256);
  // K8: P = xn2 @ WBp^T
  gemm_reg64<float,false,false,false><<<dim3(8,32), 256, 0, stream>>>(Aext, WBp, P, nullptr, nullptr, 768, 1312, 768, 512);
  // K9: inter + g -> Aext cols 768..1311
  build_g<<<dim3(NTOK/4), 256, 0, stream>>>(HAB, P, hB_b2, Aext);
  // K10: H = relu(Aext @ Wc^T)   (base + adapt + biases fused; LDS path)
  gemm_bt<bf16,true,false,false><<<dim3(24,32), 256, 0, stream>>>(Aext, Wc, Hbuf, nullptr, nullptr, 1312, 1312, 1312, 3072);
  // K11: out = src2 + H @ ffn2_w^T + ffn2_b  (register path)
  gemm_reg64<float,false,true,true><<<dim3(12,32), 256, 0, stream>>>(Hbuf, W2, out, ffn2_b, Src2, 3072, 3072, 3072, 768);
}

// Round 8
// 332.548 us; speedup vs baseline: 1.4984x; 1.4984x over previous
//
#include <hip/hip_runtime.h>
#include <math.h>

// ---- problem constants ----
#define NB 2
#define NS 2048
#define NE 768
#define NF 3072
#define NHEAD 12
#define NTOK 4096   // B*S

typedef __bf16 bf16;
typedef __bf16 bf16x4 __attribute__((ext_vector_type(4)));
typedef __bf16 bf16x8 __attribute__((ext_vector_type(8)));
typedef float  f32x4  __attribute__((ext_vector_type(4)));

__device__ __forceinline__ f32x4 mfma_bf16(bf16x8 a, bf16x8 b, f32x4 c) {
  return __builtin_amdgcn_mfma_f32_16x16x32_bf16(a, b, c, 0, 0, 0);
}

__device__ __forceinline__ float fast_exp2(float x) {
#if __has_builtin(__builtin_amdgcn_exp2f)
  return __builtin_amdgcn_exp2f(x);
#else
  return exp2f(x);
#endif
}

// async global->LDS, 16B per lane. LDS dest must be wave-uniform base + lane*16.
__device__ __forceinline__ void glds16(const void* g, void* l) {
  __builtin_amdgcn_global_load_lds((const __attribute__((address_space(1))) void*)g,
                                   (__attribute__((address_space(3))) void*)l,
                                   16, 0, 0);
}

// XCD-band swizzle: block i -> XCD i&7 (round-robin dispatch assumption); give
// each XCD a contiguous band of gridDim.y/8 M-panels for L2 A-reuse.
// Requires gridDim.y % 8 == 0 (true for all launches here).
__device__ __forceinline__ void swz_xy(int& bx, int& by) {
  int gx = gridDim.x;
  int i = by*gx + bx;
  int xcd = i & 7, s = i >> 3;
  int bands = gridDim.y >> 3;
  by = xcd*bands + s / gx;
  bx = s % gx;
}

// ---------------- weight prep: fp32 -> bf16 (+ reshapes/concat) ----------------
__global__ void prep_kernel(const float* __restrict__ in_proj, const float* __restrict__ out_proj,
                            const float* __restrict__ ffn1_w, const float* __restrict__ ffn1_b,
                            const float* __restrict__ ffn2_w,
                            const float* __restrict__ hA_w1, const float* __restrict__ hA_b1,
                            const float* __restrict__ hA_w2, const float* __restrict__ hA_b2,
                            const float* __restrict__ hB_w1, const float* __restrict__ hB_b1,
                            const float* __restrict__ hB_w2,
                            const float* __restrict__ task,
                            bf16* __restrict__ Wqkv, bf16* __restrict__ Wo, bf16* __restrict__ W2,
                            bf16* __restrict__ W1ab, float* __restrict__ b1ab,
                            bf16* __restrict__ WBp, bf16* __restrict__ Wc,
                            bf16* __restrict__ task_bf)
{
  __shared__ float tb[64*130];
  int stride = gridDim.x * blockDim.x;
  int t0 = blockIdx.x * blockDim.x + threadIdx.x;
  // q rows (first 768) pre-scaled by (1/sqrt(HD)) * log2(e) so flash can use exp2
  const float QS = 0.125f * 1.44269504088896f;
  for (int i = t0; i < 2304*768; i += stride)
    Wqkv[i] = (bf16)(i < 768*768 ? in_proj[i] * QS : in_proj[i]);
  for (int i = t0; i < 768*768;  i += stride) Wo[i]   = (bf16)out_proj[i];
  for (int i = t0; i < 768*3072; i += stride) W2[i]   = (bf16)ffn2_w[i];
  for (int i = t0; i < 256*128;  i += stride)
    W1ab[i] = (bf16)(i < 128*128 ? hA_w1[i] : hB_w1[i - 128*128]);
  for (int i = t0; i < 256; i += stride) b1ab[i] = (i < 128) ? hA_b1[i] : hB_b1[i-128];
  for (int i = t0; i < NTOK*128; i += stride) task_bf[i] = (bf16)task[i];

  // WBp[n=(r*128+h)][e] = hB_w2[r*768+e][h] via 64x128 LDS transpose (coalesced both sides)
  for (int j0 = blockIdx.x*64; j0 < 3072; j0 += gridDim.x*64) {
    __syncthreads();
    for (int i = threadIdx.x; i < 64*128; i += 256) {
      int jr = i >> 7, hh = i & 127;
      tb[jr*130 + hh] = hB_w2[(long)(j0 + jr)*128 + hh];
    }
    __syncthreads();
    int r = j0 / 768, e0 = j0 % 768;
    for (int i = threadIdx.x; i < 128*64; i += 256) {
      int hh = i >> 6, jr = i & 63;
      WBp[(long)(r*128 + hh)*768 + e0 + jr] = (bf16)tb[jr*130 + hh];
    }
  }

  // Wc[f][0:768]=ffn1_w ; [768+h*4+r]=hA_w2[(f*4+r)][h] ; [1280+r]=hA_b2[f*4+r] ;
  // [1284]=ffn1_b[f] ; [1285:1312]=0.   hA_w2 read contiguously (i = r*128+h).
  for (int f = blockIdx.x; f < 3072; f += gridDim.x) {
    const float* hrow = hA_w2 + (long)f*512;
    bf16* wrow = Wc + (long)f*1312;
    for (int c = threadIdx.x; c < 768; c += 256) wrow[c] = (bf16)ffn1_w[(long)f*768 + c];
    for (int i = threadIdx.x; i < 512; i += 256) {
      int r = i >> 7, h = i & 127;
      wrow[768 + h*4 + r] = (bf16)hrow[i];
    }
    if (threadIdx.x < 4)        wrow[1280 + threadIdx.x] = (bf16)hA_b2[f*4 + threadIdx.x];
    else if (threadIdx.x == 4)  wrow[1284] = (bf16)ffn1_b[f];
    else if (threadIdx.x < 32)  wrow[1280 + threadIdx.x] = (bf16)0.f;
  }
}

// ---------------- RMSNorm (fp32 in -> bf16 out, arbitrary out row stride) ------
__global__ __launch_bounds__(256) void rmsnorm_k(const float* __restrict__ x,
                                                 const float* __restrict__ w,
                                                 bf16* __restrict__ out, int ld_out)
{
  __shared__ float red[4];
  long t = blockIdx.x;
  const float* xr = x + t*NE;
  float ss = 0.f;
  #pragma unroll
  for (int i = 0; i < 3; i++) { float v = xr[threadIdx.x + i*256]; ss += v*v; }
  #pragma unroll
  for (int d = 1; d < 64; d <<= 1) ss += __shfl_xor(ss, d, 64);
  if ((threadIdx.x & 63) == 0) red[threadIdx.x >> 6] = ss;
  __syncthreads();
  float tot = red[0] + red[1] + red[2] + red[3];
  float scale = rsqrtf(tot * (1.f/768.f) + 1.1920928955078125e-07f);
  #pragma unroll
  for (int i = 0; i < 3; i++) {
    int idx = threadIdx.x + i*256;
    out[t*ld_out + idx] = (bf16)(xr[idx] * scale * w[idx]);
  }
}

// ---------------- 128x128 bf16 GEMM (LDS path), C = A * B^T -------------------
// Used for K10 (compute-densest; 3 blocks/CU).
template<typename OutT, bool RELU, bool BIAS, bool RES>
__global__ __launch_bounds__(256) void gemm_bt(const bf16* __restrict__ A,
                                               const bf16* __restrict__ Bm,
                                               OutT* __restrict__ C,
                                               const float* __restrict__ bias,
                                               const float* __restrict__ res,
                                               int K, int lda, int ldb, int ldc)
{
  __shared__ bf16 As[2][128*32];
  __shared__ bf16 Bs[2][128*32];
  const int tid = threadIdx.x;
  int bx = blockIdx.x, by = blockIdx.y;
  swz_xy(bx, by);
  const int m0 = by * 128;
  const int n0 = bx * 128;
  const int w = tid >> 6, lane = tid & 63;
  const int quad = lane >> 4, l16 = lane & 15;
  const int wy = w >> 1, wx = w & 1;

  f32x4 acc[4][4];
  #pragma unroll
  for (int i = 0; i < 4; i++)
    #pragma unroll
    for (int j = 0; j < 4; j++) acc[i][j] = (f32x4){0.f,0.f,0.f,0.f};

  const int c0 = tid, c1 = tid + 256;
  const bf16* pA0 = A  + (long)(m0 + (c0 >> 2))*lda + (c0 & 3)*8;
  const bf16* pA1 = A  + (long)(m0 + (c1 >> 2))*lda + (c1 & 3)*8;
  const bf16* pB0 = Bm + (long)(n0 + (c0 >> 2))*ldb + (c0 & 3)*8;
  const bf16* pB1 = Bm + (long)(n0 + (c1 >> 2))*ldb + (c1 & 3)*8;
  auto stage = [&](int buf) {
    glds16(pA0, (void*)(&As[buf][c0*8]));
    glds16(pA1, (void*)(&As[buf][c1*8]));
    glds16(pB0, (void*)(&Bs[buf][c0*8]));
    glds16(pB1, (void*)(&Bs[buf][c1*8]));
    pA0 += 32; pA1 += 32; pB0 += 32; pB1 += 32;
  };

  stage(0);
  __builtin_amdgcn_s_waitcnt(0);
  __syncthreads();

  const int nsteps = K >> 5;
  for (int s = 0; s < nsteps; ++s) {
    const int cur = s & 1;
    if (s + 1 < nsteps) stage(cur ^ 1);

    bf16x8 af[4], bfr[4];
    #pragma unroll
    for (int mi = 0; mi < 4; ++mi)
      af[mi] = *(const bf16x8*)(&As[cur][(wy*64 + mi*16 + l16)*32 + quad*8]);
    #pragma unroll
    for (int ni = 0; ni < 4; ++ni)
      bfr[ni] = *(const bf16x8*)(&Bs[cur][(wx*64 + ni*16 + l16)*32 + quad*8]);
    #pragma unroll
    for (int mi = 0; mi < 4; ++mi)
      #pragma unroll
      for (int ni = 0; ni < 4; ++ni)
        acc[mi][ni] = mfma_bf16(af[mi], bfr[ni], acc[mi][ni]);

    __builtin_amdgcn_s_waitcnt(0);
    __syncthreads();
  }

  #pragma unroll
  for (int mi = 0; mi < 4; ++mi)
    #pragma unroll
    for (int ni = 0; ni < 4; ++ni) {
      int col = n0 + wx*64 + ni*16 + l16;
      #pragma unroll
      for (int r = 0; r < 4; ++r) {
        long row = m0 + wy*64 + mi*16 + quad*4 + r;
        float v = acc[mi][ni][r];
        if (BIAS) v += bias[col];
        if (RES)  v += res[row*ldc + col];
        if (RELU) v = v > 0.f ? v : 0.f;
        C[row*ldc + col] = (OutT)v;
      }
    }
}

// ---------------- 64x64-tile GEMM, BK=64, XOR-swizzled LDS --------------------
// 4 waves of 32Mx32N. 64-elem rows = 8 chunks of 16B, chunk swizzled by row&7
// (flash-verified pattern) -> conflict-free ds_read_b128. Grid has 4x the
// blocks of the 128-tile variant -> 3+ blocks/CU (latency-overlap partners),
// and BK=64 halves the number of barrier drains. K % 64 == 0.
template<typename OutT, bool RELU, bool BIAS, bool RES>
__global__ __launch_bounds__(256) void gemm64(const bf16* __restrict__ A,
                                              const bf16* __restrict__ Bm,
                                              OutT* __restrict__ C,
                                              const float* __restrict__ bias,
                                              const float* __restrict__ res,
                                              int K, int lda, int ldb, int ldc)
{
  __shared__ bf16 As[2][64*64];
  __shared__ bf16 Bs[2][64*64];
  const int tid = threadIdx.x;
  int bx = blockIdx.x, by = blockIdx.y;
  swz_xy(bx, by);
  const int m0 = by * 64, n0 = bx * 64;
  const int w = tid >> 6, lane = tid & 63;
  const int quad = lane >> 4, l16 = lane & 15;
  const int wy = w >> 1, wx = w & 1;     // wave tile: 32M x 32N
  const int sw = l16 & 7;                // fragment-read swizzle

  f32x4 acc[2][2];
  #pragma unroll
  for (int i = 0; i < 2; i++)
    #pragma unroll
    for (int j = 0; j < 2; j++) acc[i][j] = (f32x4){0.f,0.f,0.f,0.f};

  const int c0 = tid, c1 = tid + 256;
  const int r0 = c0 >> 3, g0 = ((c0 & 7) ^ (r0 & 7)) * 8;
  const int r1 = c1 >> 3, g1 = ((c1 & 7) ^ (r1 & 7)) * 8;
  const bf16* pA0 = A  + (long)(m0 + r0)*lda + g0;
  const bf16* pA1 = A  + (long)(m0 + r1)*lda + g1;
  const bf16* pB0 = Bm + (long)(n0 + r0)*ldb + g0;
  const bf16* pB1 = Bm + (long)(n0 + r1)*ldb + g1;
  auto stage = [&](int buf) {
    glds16(pA0, (void*)(&As[buf][c0*8]));
    glds16(pA1, (void*)(&As[buf][c1*8]));
    glds16(pB0, (void*)(&Bs[buf][c0*8]));
    glds16(pB1, (void*)(&Bs[buf][c1*8]));
    pA0 += 64; pA1 += 64; pB0 += 64; pB1 += 64;
  };

  stage(0);
  __builtin_amdgcn_s_waitcnt(0);
  __syncthreads();

  const int nsteps = K >> 6;
  for (int s = 0; s < nsteps; ++s) {
    const int cur = s & 1;
    if (s + 1 < nsteps) stage(cur ^ 1);

    bf16x8 af[2][2], bfr[2][2];
    #pragma unroll
    for (int mi = 0; mi < 2; ++mi)
      #pragma unroll
      for (int kb = 0; kb < 2; ++kb)
        af[mi][kb] = *(const bf16x8*)(&As[cur][(wy*32 + mi*16 + l16)*64 + (((kb*4 + quad) ^ sw))*8]);
    #pragma unroll
    for (int ni = 0; ni < 2; ++ni)
      #pragma unroll
      for (int kb = 0; kb < 2; ++kb)
        bfr[ni][kb] = *(const bf16x8*)(&Bs[cur][(wx*32 + ni*16 + l16)*64 + (((kb*4 + quad) ^ sw))*8]);
    #pragma unroll
    for (int kb = 0; kb < 2; ++kb)
      #pragma unroll
      for (int mi = 0; mi < 2; ++mi)
        #pragma unroll
        for (int ni = 0; ni < 2; ++ni)
          acc[mi][ni] = mfma_bf16(af[mi][kb], bfr[ni][kb], acc[mi][ni]);

    __builtin_amdgcn_s_waitcnt(0);
    __syncthreads();
  }

  #pragma unroll
  for (int mi = 0; mi < 2; ++mi)
    #pragma unroll
    for (int ni = 0; ni < 2; ++ni) {
      int col = n0 + wx*32 + ni*16 + l16;
      #pragma unroll
      for (int r = 0; r < 4; ++r) {
        long row = m0 + wy*32 + mi*16 + quad*4 + r;
        float v = acc[mi][ni][r];
        if (BIAS) v += bias[col];
        if (RES)  v += res[row*ldc + col];
        if (RELU) v = v > 0.f ? v : 0.f;
        C[row*ldc + col] = (OutT)v;
      }
    }
}

// ---- QKV GEMM: 64x64-tile variant with split epilogue:
// cols<1536 -> Qkv[t][2304]; V block -> Vt[bh][d][s] directly.
__global__ __launch_bounds__(256) void gemm_qkv64(const bf16* __restrict__ A,
                                                  const bf16* __restrict__ Bm,
                                                  bf16* __restrict__ Qkv,
                                                  bf16* __restrict__ Vt)
{
  __shared__ bf16 As[2][64*64];
  __shared__ bf16 Bs[2][64*64];
  const int tid = threadIdx.x;
  int bx = blockIdx.x, by = blockIdx.y;
  swz_xy(bx, by);
  const int m0 = by * 64, n0 = bx * 64;
  const int w = tid >> 6, lane = tid & 63;
  const int quad = lane >> 4, l16 = lane & 15;
  const int wy = w >> 1, wx = w & 1;
  const int sw = l16 & 7;

  f32x4 acc[2][2];
  #pragma unroll
  for (int i = 0; i < 2; i++)
    #pragma unroll
    for (int j = 0; j < 2; j++) acc[i][j] = (f32x4){0.f,0.f,0.f,0.f};

  const int c0 = tid, c1 = tid + 256;
  const int r0 = c0 >> 3, g0 = ((c0 & 7) ^ (r0 & 7)) * 8;
  const int r1 = c1 >> 3, g1 = ((c1 & 7) ^ (r1 & 7)) * 8;
  const bf16* pA0 = A  + (long)(m0 + r0)*768 + g0;
  const bf16* pA1 = A  + (long)(m0 + r1)*768 + g1;
  const bf16* pB0 = Bm + (long)(n0 + r0)*768 + g0;
  const bf16* pB1 = Bm + (long)(n0 + r1)*768 + g1;
  auto stage = [&](int buf) {
    glds16(pA0, (void*)(&As[buf][c0*8]));
    glds16(pA1, (void*)(&As[buf][c1*8]));
    glds16(pB0, (void*)(&Bs[buf][c0*8]));
    glds16(pB1, (void*)(&Bs[buf][c1*8]));
    pA0 += 64; pA1 += 64; pB0 += 64; pB1 += 64;
  };

  stage(0);
  __builtin_amdgcn_s_waitcnt(0);
  __syncthreads();

  for (int s = 0; s < 12; ++s) {           // K=768
    const int cur = s & 1;
    if (s + 1 < 12) stage(cur ^ 1);

    bf16x8 af[2][2], bfr[2][2];
    #pragma unroll
    for (int mi = 0; mi < 2; ++mi)
      #pragma unroll
      for (int kb = 0; kb < 2; ++kb)
        af[mi][kb] = *(const bf16x8*)(&As[cur][(wy*32 + mi*16 + l16)*64 + (((kb*4 + quad) ^ sw))*8]);
    #pragma unroll
    for (int ni = 0; ni < 2; ++ni)
      #pragma unroll
      for (int kb = 0; kb < 2; ++kb)
        bfr[ni][kb] = *(const bf16x8*)(&Bs[cur][(wx*32 + ni*16 + l16)*64 + (((kb*4 + quad) ^ sw))*8]);
    #pragma unroll
    for (int kb = 0; kb < 2; ++kb)
      #pragma unroll
      for (int mi = 0; mi < 2; ++mi)
        #pragma unroll
        for (int ni = 0; ni < 2; ++ni)
          acc[mi][ni] = mfma_bf16(af[mi][kb], bfr[ni][kb], acc[mi][ni]);

    __builtin_amdgcn_s_waitcnt(0);
    __syncthreads();
  }

  const int bb = m0 >> 11;                  // batch (tile is 2048-aligned)
  #pragma unroll
  for (int mi = 0; mi < 2; ++mi)
    #pragma unroll
    for (int ni = 0; ni < 2; ++ni) {
      int col = n0 + wx*32 + ni*16 + l16;
      #pragma unroll
      for (int r = 0; r < 4; ++r) {
        long row = m0 + wy*32 + mi*16 + quad*4 + r;
        bf16 v = (bf16)acc[mi][ni][r];
        if (col < 1536) {
          Qkv[row*2304 + col] = v;
        } else {
          int vc = col - 1536;
          int hh = vc >> 6, d = vc & 63;
          long srow = row & (NS-1);
          Vt[((long)(bb*NHEAD + hh)*64 + d)*NS + srow] = v;
        }
      }
    }
}

// ---------------- flash attention v3: register-resident P ----------------------
// S^T = mfma(K, Q); S^T's C-layout (q=l16, kv=quad*4+r) IS the PV A-operand
// layout under k-mapping j<4 -> quad*4+j, j>=4 -> 16+quad*4+(j-4).
// No online-softmax (|s|<~5, exp2 safe, shift-invariant). q pre-scaled by
// 0.125*log2e. XOR-swizzled K/V LDS, dbuf staging.
__global__ __launch_bounds__(256) void flash_attn(const bf16* __restrict__ Qkv,
                                                  const bf16* __restrict__ Vt,
                                                  bf16* __restrict__ Ctx)
{
  __shared__ bf16 Ks[2][64*64];
  __shared__ bf16 Vs[2][64*64];
  __shared__ float Ls[4][16];

  const int tid = threadIdx.x;
  const int w = tid >> 6, lane = tid & 63;
  const int quad = lane >> 4, l16 = lane & 15;
  const int bh = blockIdx.y;
  const int b = bh / NHEAD, h = bh % NHEAD;
  const int q0 = blockIdx.x * 64;
  const long tq = (long)(b*NS + q0 + w*16 + l16);

  bf16x8 qf[2];   // q pre-scaled by 0.125*log2e via Wqkv
  qf[0] = *(const bf16x8*)(Qkv + tq*2304 + h*64 + quad*8);
  qf[1] = *(const bf16x8*)(Qkv + tq*2304 + h*64 + 32 + quad*8);

  f32x4 o[4];
  float lsum = 0.f;
  #pragma unroll
  for (int i = 0; i < 4; i++) o[i] = (f32x4){0.f,0.f,0.f,0.f};

  const int c0 = tid, c1 = tid + 256;
  const int r0 = c0 >> 3, g0 = ((c0 & 7) ^ (r0 & 7)) * 8;
  const int r1 = c1 >> 3, g1 = ((c1 & 7) ^ (r1 & 7)) * 8;
  const bf16* kp0 = Qkv + (long)(b*NS + r0)*2304 + 768 + h*64 + g0;
  const bf16* kp1 = Qkv + (long)(b*NS + r1)*2304 + 768 + h*64 + g1;
  const bf16* vp0 = Vt + ((long)bh*64 + r0)*NS + g0;
  const bf16* vp1 = Vt + ((long)bh*64 + r1)*NS + g1;

  auto stage = [&](int buf) {
    glds16(kp0, (void*)(&Ks[buf][c0*8]));
    glds16(kp1, (void*)(&Ks[buf][c1*8]));
    glds16(vp0, (void*)(&Vs[buf][c0*8]));
    glds16(vp1, (void*)(&Vs[buf][c1*8]));
    kp0 += 64*2304; kp1 += 64*2304; vp0 += 64; vp1 += 64;
  };

  stage(0);
  __builtin_amdgcn_s_waitcnt(0);
  __syncthreads();

  for (int t = 0; t < NS/64; ++t) {
    const int cur = t & 1;
    if (t + 1 < NS/64) stage(cur ^ 1);

    // S^T = K Q^T : s[nt] holds kv = nt*16 + quad*4 + r, q = l16
    f32x4 s[4];
    #pragma unroll
    for (int nt = 0; nt < 4; ++nt) {
      s[nt] = (f32x4){0.f,0.f,0.f,0.f};
      #pragma unroll
      for (int kb = 0; kb < 2; ++kb) {
        bf16x8 kf = *(const bf16x8*)(&Ks[cur][(nt*16 + l16)*64 + (((kb*4 + quad) ^ (l16 & 7)))*8]);
        s[nt] = mfma_bf16(kf, qf[kb], s[nt]);   // A=K, B=Q -> S^T
      }
    }
    // P = exp2(S^T) in registers; pack straight into PV A-fragments
    bf16x8 pf[2];
    #pragma unroll
    for (int nt = 0; nt < 4; ++nt)
      #pragma unroll
      for (int r = 0; r < 4; ++r) {
        float p = fast_exp2(s[nt][r]);
        lsum += p;
        pf[nt >> 1][(nt & 1)*4 + r] = (bf16)p;
      }
    // PV: o[dt] += P * V   (B-frag: two b64 reads from Vs, 16 kv apart)
    #pragma unroll
    for (int ntp = 0; ntp < 2; ++ntp)
      #pragma unroll
      for (int dt = 0; dt < 4; ++dt) {
        int row = dt*16 + l16;                       // d
        int cA = ntp*4 + (quad >> 1);
        int base = row*64 + (quad & 1)*4;
        bf16x4 va = *(const bf16x4*)(&Vs[cur][base + ((cA       ^ (row & 7)) << 3)]);
        bf16x4 vb = *(const bf16x4*)(&Vs[cur][base + (((cA + 2) ^ (row & 7)) << 3)]);
        bf16x8 vf = {va[0],va[1],va[2],va[3], vb[0],vb[1],vb[2],vb[3]};
        o[dt] = mfma_bf16(pf[ntp], vf, o[dt]);
      }

    __builtin_amdgcn_s_waitcnt(0);
    __syncthreads();
  }

  // row sums: lane holds q=l16; reduce over quads, then redistribute via LDS
  lsum += __shfl_xor(lsum, 16, 64);
  lsum += __shfl_xor(lsum, 32, 64);
  if (quad == 0) Ls[w][l16] = lsum;       // wave-private
  #pragma unroll
  for (int r = 0; r < 4; ++r) {
    float inv = 1.f / Ls[w][quad*4 + r];
    long trow = (long)(b*NS + q0 + w*16 + quad*4 + r);
    #pragma unroll
    for (int dt = 0; dt < 4; ++dt)
      Ctx[trow*NE + h*64 + dt*16 + l16] = (bf16)(o[dt][r] * inv);
  }
}

// ---------------- per-token: inter + build g/ones/zeros cols of Aext -----------
// 4 waves/block, one token per wave.
__global__ __launch_bounds__(256) void build_g(const bf16* __restrict__ HAB,
                                               const float* __restrict__ P,
                                               const float* __restrict__ hB_b2,
                                               bf16* __restrict__ Aext)
{
  long t = blockIdx.x*4 + (threadIdx.x >> 6);
  int lane = threadIdx.x & 63;
  const bf16* xr = Aext + t*1312;            // cols 0..767 = xn2
  float acc[4] = {0.f, 0.f, 0.f, 0.f};
  for (int i = lane; i < 768; i += 64) {
    float xv = (float)xr[i];
    #pragma unroll
    for (int r = 0; r < 4; ++r) acc[r] += xv * hB_b2[r*768 + i];
  }
  const bf16* hB = HAB + t*256 + 128;
  const float* Pr = P + t*512;
  #pragma unroll
  for (int k = 0; k < 2; ++k) {
    int h = lane + k*64;
    float hv = (float)hB[h];
    #pragma unroll
    for (int r = 0; r < 4; ++r) acc[r] += hv * Pr[r*128 + h];
  }
  #pragma unroll
  for (int r = 0; r < 4; ++r)
    #pragma unroll
    for (int d = 1; d < 64; d <<= 1) acc[r] += __shfl_xor(acc[r], d, 64);

  bf16* grow = Aext + t*1312 + 768;
  const bf16* hA = HAB + t*256;
  #pragma unroll
  for (int j = 0; j < 8; ++j) {
    int idx = lane*8 + j;                    // 0..511
    int h = idx >> 2, r = idx & 3;
    grow[idx] = (bf16)((float)hA[h] * acc[r]);
  }
  if (lane < 4)       Aext[t*1312 + 1280 + lane] = (bf16)acc[lane];
  else if (lane == 4) Aext[t*1312 + 1284] = (bf16)1.0f;
  else if (lane < 32) Aext[t*1312 + 1280 + lane] = (bf16)0.f;
}

// ---------------- host launcher ----------------
extern "C" void kernel_launch(void* const* d_in, const int* in_sizes, int n_in,
                              void* d_out, int out_size, void* d_ws, size_t ws_size,
                              hipStream_t stream)
{
  const float* src      = (const float*)d_in[0];
  const float* task     = (const float*)d_in[1];
  const float* norm1_w  = (const float*)d_in[2];
  const float* norm2_w  = (const float*)d_in[3];
  const float* in_proj  = (const float*)d_in[4];
  const float* out_proj = (const float*)d_in[5];
  const float* ffn1_w   = (const float*)d_in[6];
  const float* ffn1_b   = (const float*)d_in[7];
  const float* ffn2_w   = (const float*)d_in[8];
  const float* ffn2_b   = (const float*)d_in[9];
  const float* hA_w1    = (const float*)d_in[10];
  const float* hA_b1    = (const float*)d_in[11];
  const float* hA_w2    = (const float*)d_in[12];
  const float* hA_b2    = (const float*)d_in[13];
  const float* hB_w1    = (const float*)d_in[14];
  const float* hB_b1    = (const float*)d_in[15];
  const float* hB_w2    = (const float*)d_in[16];
  const float* hB_b2    = (const float*)d_in[17];
  float* out = (float*)d_out;

  char* ws = (char*)d_ws;
  size_t off = 0;
  auto alloc = [&](size_t bytes) { size_t o = off; off += (bytes + 255) & ~(size_t)255; return o; };
  bf16*  Wqkv   = (bf16*)(ws + alloc(2304*768*2));
  bf16*  Wo     = (bf16*)(ws + alloc(768*768*2));
  bf16*  W2     = (bf16*)(ws + alloc(768*3072*2));
  bf16*  W1ab   = (bf16*)(ws + alloc(256*128*2));
  float* b1ab   = (float*)(ws + alloc(256*4));
  bf16*  WBp    = (bf16*)(ws + alloc(512*768*2));
  bf16*  Wc     = (bf16*)(ws + alloc(3072*1312*2));
  bf16*  taskbf = (bf16*)(ws + alloc((size_t)NTOK*128*2));
  bf16*  XC     = (bf16*)(ws + alloc((size_t)NTOK*768*2));    // Xn1, then Ctx
  char*  QKVH   = ws + alloc(25165824);                        // Qkv(18874368)+Vt(6291456) / Hbuf
  bf16*  Qkv    = (bf16*)QKVH;
  bf16*  Vt     = (bf16*)(QKVH + 18874368);
  bf16*  Hbuf   = (bf16*)QKVH;
  float* Src2   = (float*)(ws + alloc((size_t)NTOK*768*4));
  bf16*  Aext   = (bf16*)(ws + alloc((size_t)NTOK*1312*2));
  bf16*  HAB    = (bf16*)(ws + alloc((size_t)NTOK*256*2));
  float* P      = (float*)(ws + alloc((size_t)NTOK*512*4));

  // K0: weight prep / casts
  prep_kernel<<<dim3(1280), 256, 0, stream>>>(in_proj, out_proj, ffn1_w, ffn1_b, ffn2_w,
      hA_w1, hA_b1, hA_w2, hA_b2, hB_w1, hB_b1, hB_w2, task,
      Wqkv, Wo, W2, W1ab, b1ab, WBp, Wc, taskbf);
  // K1: x1 = rmsnorm(src, norm1_w) -> bf16
  rmsnorm_k<<<dim3(NTOK), 256, 0, stream>>>(src, norm1_w, XC, 768);
  // K2: qkv = x1 @ in_proj^T ; V block written directly to Vt
  gemm_qkv64<<<dim3(36,64), 256, 0, stream>>>(XC, Wqkv, Qkv, Vt);
  // K4: flash attention -> Ctx (reuses XC)
  flash_attn<<<dim3(32,24), 256, 0, stream>>>(Qkv, Vt, XC);
  // K5: src2 = src + ctx @ out_proj^T
  gemm64<float,false,false,true><<<dim3(12,64), 256, 0, stream>>>(XC, Wo, Src2, nullptr, src, 768, 768, 768, 768);
  // K6: xn2 = rmsnorm(src2, norm2_w) -> Aext cols 0..767 (stride 1312)
  rmsnorm_k<<<dim3(NTOK), 256, 0, stream>>>(Src2, norm2_w, Aext, 1312);
  // K7: HAB = relu(task @ W1ab^T + b1ab)
  gemm64<bf16,true,true,false><<<dim3(4,64), 256, 0, stream>>>(taskbf, W1ab, HAB, b1ab, nullptr, 128, 128, 128, 256);
  // K8: P = xn2 @ WBp^T
  gemm64<float,false,false,false><<<dim3(8,64), 256, 0, stream>>>(Aext, WBp, P, nullptr, nullptr, 768, 1312, 768, 512);
  // K9: inter + g -> Aext cols 768..1311
  build_g<<<dim3(NTOK/4), 256, 0, stream>>>(HAB, P, hB_b2, Aext);
  // K10: H = relu(Aext @ Wc^T)   (base + adapt + biases fused; 128-tile LDS path)
  gemm_bt<bf16,true,false,false><<<dim3(24,32), 256, 0, stream>>>(Aext, Wc, Hbuf, nullptr, nullptr, 1312, 1312, 1312, 3072);
  // K11: out = src2 + H @ ffn2_w^T + ffn2_b  (64-tile path)
  gemm64<float,false,true,true><<<dim3(12,64), 256, 0, stream>>>(Hbuf, W2, out, ffn2_b, Src2, 3072, 3072, 3072, 768);
}